// Round 3
// baseline (114.613 us; speedup 1.0000x reference)
//
#include <hip/hip_runtime.h>
#include <math.h>

// TopLeftPool: p[b,c,i,j] = max_{h>=i, w>=j} x[b,c,h,w]  (reverse cummax H, then W)
//
// One 64-lane wave per 128x128 map, streaming bottom-up, 8 rows per batch.
// Column->lane mapping is REVERSED (lane l owns cols {126-2l, 127-2l}) so the
// W-direction suffix-max becomes a lane-PREFIX-max, computable entirely with
// the standard GFX9 DPP scan (row_shr 1/2/4/8 + row_bcast15/31) -- pure VALU,
// zero LDS ops. H-direction carry is 2 lane-local fmax per row.
//
// Per batch: 8 descending-address dwordx2 loads (4KB contiguous burst, waits
// resolve incrementally since compute consumes in issue order), 8 scans, 8
// dwordx2 stores.

#define N_MAPS (16 * 256)
#define W 128
#define BATCH 8

// m = fmax(m, dpp_select(m)); lanes with invalid source / masked rows keep m
// (identity under max).
template <int CTRL, int ROW_MASK>
__device__ __forceinline__ float dpp_max(float m) {
    int t = __builtin_amdgcn_update_dpp(__float_as_int(m), __float_as_int(m),
                                        CTRL, ROW_MASK, 0xF, false);
    return fmaxf(m, __int_as_float(t));
}

__global__ __launch_bounds__(256) void
TopLeftPool_54357106098212_kernel(const float* __restrict__ x,
                                  float* __restrict__ out) {
    const int tid  = (int)(blockIdx.x * blockDim.x + threadIdx.x);
    const int wave = tid >> 6;
    const int lane = (int)(threadIdx.x & 63);
    if (wave >= N_MAPS) return;

    // Reversed column mapping: lane l covers columns {126-2l, 127-2l}.
    const size_t base = (size_t)wave * (W * W) + (size_t)(126 - 2 * lane);
    const float* __restrict__ xp = x + base;
    float* __restrict__ op = out + base;

    float cx = -INFINITY, cy = -INFINITY;   // H-carry for this lane's 2 columns

    for (int b = (W / BATCH) - 1; b >= 0; --b) {
        float2 v[BATCH];
        // Issue loads in descending row order (consumed in the same order ->
        // incremental vmcnt waits). 4KB contiguous burst per wave.
        #pragma unroll
        for (int i = BATCH - 1; i >= 0; --i) {
            v[i] = *reinterpret_cast<const float2*>(
                xp + (size_t)(b * BATCH + i) * W);
        }

        #pragma unroll
        for (int i = BATCH - 1; i >= 0; --i) {
            const float a  = v[i].x;           // col 126-2l
            const float bb = v[i].y;           // col 127-2l
            const float lm = fmaxf(a, bb);     // lane max

            // Exclusive-prefix input: z = lanemax from lane-1; lane 0 -> -inf.
            int sh = __builtin_amdgcn_update_dpp(
                __float_as_int(lm), __float_as_int(lm), 0x138 /*wave_shr:1*/,
                0xF, 0xF, false);
            float e = (lane == 0) ? -INFINITY : __int_as_float(sh);

            // Inclusive prefix-max scan of z over 64 lanes -> E (exclusive
            // prefix of lanemax): row_shr 1/2/4/8, bcast15 (rows 1,3),
            // bcast31 (rows 2,3). All VALU.
            e = dpp_max<0x111, 0xF>(e);
            e = dpp_max<0x112, 0xF>(e);
            e = dpp_max<0x114, 0xF>(e);
            e = dpp_max<0x118, 0xF>(e);
            e = dpp_max<0x142, 0xA>(e);   // row_bcast15 -> lanes 16-31, 48-63
            e = dpp_max<0x143, 0xC>(e);   // row_bcast31 -> lanes 32-63

            // Row suffix values at this lane's two columns.
            const float Sx = fmaxf(lm, e);   // = max(a, b, E)
            const float Sy = fmaxf(bb, e);

            // Fold H-carry and emit.
            cx = fmaxf(cx, Sx);
            cy = fmaxf(cy, Sy);
            float2 o; o.x = cx; o.y = cy;
            *reinterpret_cast<float2*>(op + (size_t)(b * BATCH + i) * W) = o;
        }
    }
}

extern "C" void kernel_launch(void* const* d_in, const int* in_sizes, int n_in,
                              void* d_out, int out_size, void* d_ws, size_t ws_size,
                              hipStream_t stream) {
    (void)in_sizes; (void)n_in; (void)out_size; (void)d_ws; (void)ws_size;
    const float* x = (const float*)d_in[0];
    float* out = (float*)d_out;

    // 4096 maps, 1 wave each, 4 waves (256 threads) per block -> 1024 blocks.
    dim3 grid(N_MAPS / 4);
    dim3 block(256);
    hipLaunchKernelGGL(TopLeftPool_54357106098212_kernel, grid, block, 0, stream,
                       x, out);
}

// Round 5
// 111.276 us; speedup vs baseline: 1.0300x; 1.0300x over previous
//
#include <hip/hip_runtime.h>
#include <math.h>

// TopLeftPool: p[b,c,i,j] = max_{h>=i, w>=j} x[b,c,h,w]  (reverse cummax H, then W)
//
// One BLOCK (4 waves) per 128x128 map; wave w owns the 32-row segment
// [32w, 32w+32). Phase 1: issue all 32 float2 row-loads (16 KB in flight per
// wave -> deep MLP), then DPP-scan each row (reversed column->lane mapping so
// the W suffix-max is a lane prefix-max; pure VALU, zero LDS ops) while
// folding the segment-local H carry, overwriting the row registers with the
// segment-local suffix-cummax. Phase 2: exchange per-column segment totals
// via 2 KB LDS + one barrier; fold totals of segments BELOW (w' > w).
// Phase 3: add fold, stream 32 coalesced 512 B stores.
//
// R4 bug fixed: x-column suffix must fold lm = max(a,b) (its right neighbor
// is in the same lane), not a alone.

#define N_MAPS (16 * 256)
#define W 128
#define SEG 32
#define NWAVES 4

// m = fmax(m, dpp_select(m)); invalid-source / masked-row lanes keep m
// (identity under max).
template <int CTRL, int ROW_MASK>
__device__ __forceinline__ float dpp_max(float m) {
    int t = __builtin_amdgcn_update_dpp(__float_as_int(m), __float_as_int(m),
                                        CTRL, ROW_MASK, 0xF, false);
    return fmaxf(m, __int_as_float(t));
}

__global__ __launch_bounds__(256, 4) void
TopLeftPool_54357106098212_kernel(const float* __restrict__ x,
                                  float* __restrict__ out) {
    __shared__ float2 totals[NWAVES][64];

    const int map  = (int)blockIdx.x;
    const int w    = (int)(threadIdx.x >> 6);   // wave id = segment id
    const int lane = (int)(threadIdx.x & 63);

    // Reversed column mapping: lane l covers columns {126-2l, 127-2l}.
    const size_t base = (size_t)map * (W * W) + (size_t)(w * SEG) * W
                        + (size_t)(126 - 2 * lane);
    const float* __restrict__ xp = x + base;
    float* __restrict__ op = out + base;

    // Phase 1a: issue every row load in the segment (descending row order,
    // matching consumption order -> incremental vmcnt waits).
    float2 v[SEG];
    #pragma unroll
    for (int i = SEG - 1; i >= 0; --i)
        v[i] = *reinterpret_cast<const float2*>(xp + (size_t)i * W);

    // Phase 1b: bottom-up segment-local scan, in place.
    float cx = -INFINITY, cy = -INFINITY;
    #pragma unroll
    for (int i = SEG - 1; i >= 0; --i) {
        const float a  = v[i].x;          // col 126-2l
        const float b  = v[i].y;          // col 127-2l
        const float lm = fmaxf(a, b);

        // Exclusive-prefix input: lanemax from lane-1 (lane 0 -> -inf).
        int sh = __builtin_amdgcn_update_dpp(
            __float_as_int(lm), __float_as_int(lm), 0x138 /*wave_shr:1*/,
            0xF, 0xF, false);
        float e = (lane == 0) ? -INFINITY : __int_as_float(sh);

        // Inclusive prefix-max scan over 64 lanes (GFX9 DPP sequence).
        e = dpp_max<0x111, 0xF>(e);   // row_shr:1
        e = dpp_max<0x112, 0xF>(e);   // row_shr:2
        e = dpp_max<0x114, 0xF>(e);   // row_shr:4
        e = dpp_max<0x118, 0xF>(e);   // row_shr:8
        e = dpp_max<0x142, 0xA>(e);   // row_bcast15 -> lanes 16-31, 48-63
        e = dpp_max<0x143, 0xC>(e);   // row_bcast31 -> lanes 32-63

        // Row-suffix values at this lane's two columns:
        //   col 127-2l: max(b, e);  col 126-2l: max(a, b, e) = max(lm, e).
        cx = fmaxf(cx, fmaxf(lm, e));
        cy = fmaxf(cy, fmaxf(b, e));
        v[i].x = cx;
        v[i].y = cy;
    }

    // Phase 2: exchange per-column segment totals; fold segments below.
    totals[w][lane] = make_float2(cx, cy);
    __syncthreads();

    float fx = -INFINITY, fy = -INFINITY;
    for (int w2 = w + 1; w2 < NWAVES; ++w2) {   // wave-uniform trip count
        const float2 t = totals[w2][lane];
        fx = fmaxf(fx, t.x);
        fy = fmaxf(fy, t.y);
    }

    // Phase 3: fold and stream out (ascending, coalesced 512 B per store).
    #pragma unroll
    for (int i = 0; i < SEG; ++i) {
        float2 o;
        o.x = fmaxf(v[i].x, fx);
        o.y = fmaxf(v[i].y, fy);
        *reinterpret_cast<float2*>(op + (size_t)i * W) = o;
    }
}

extern "C" void kernel_launch(void* const* d_in, const int* in_sizes, int n_in,
                              void* d_out, int out_size, void* d_ws, size_t ws_size,
                              hipStream_t stream) {
    (void)in_sizes; (void)n_in; (void)out_size; (void)d_ws; (void)ws_size;
    const float* x = (const float*)d_in[0];
    float* out = (float*)d_out;

    // One block per map.
    dim3 grid(N_MAPS);
    dim3 block(64 * NWAVES);
    hipLaunchKernelGGL(TopLeftPool_54357106098212_kernel, grid, block, 0, stream,
                       x, out);
}

// Round 6
// 82.523 us; speedup vs baseline: 1.3889x; 1.3484x over previous
//
#include <hip/hip_runtime.h>
#include <math.h>

// TopLeftPool: p[b,c,i,j] = max_{h>=i, w>=j} x[b,c,h,w]  (reverse cummax H, then W)
//
// One BLOCK (8 waves, 512 threads) per 128x128 map; wave w owns the 16-row
// segment [16w, 16w+16). Per wave: issue all 16 float2 row-loads (8 KB in
// flight), DPP-scan each row (reversed column->lane mapping makes the W
// suffix-max a lane prefix-max -> pure VALU, zero LDS ops in the scan) while
// folding the segment-local H carry. Exchange per-column segment totals via
// 4 KB LDS + one barrier, fold totals of segments below, then stream 16
// coalesced NON-TEMPORAL 512 B stores (output bypasses L3 so the 256 MiB
// input stays L3-resident across graph replays).
//
// Occupancy: ~55 VGPR under __launch_bounds__(512,8) -> 8 waves/SIMD,
// 32 waves/CU (2x every previous round). Serial H-chain: 16 rows.

#define N_MAPS (16 * 256)
#define W 128
#define SEG 16
#define NWAVES 8

typedef float f32x2 __attribute__((ext_vector_type(2)));

// m = fmax(m, dpp_select(m)); invalid-source / masked-row lanes keep m
// (identity under max).
template <int CTRL, int ROW_MASK>
__device__ __forceinline__ float dpp_max(float m) {
    int t = __builtin_amdgcn_update_dpp(__float_as_int(m), __float_as_int(m),
                                        CTRL, ROW_MASK, 0xF, false);
    return fmaxf(m, __int_as_float(t));
}

__global__ __launch_bounds__(512, 8) void
TopLeftPool_54357106098212_kernel(const float* __restrict__ x,
                                  float* __restrict__ out) {
    __shared__ f32x2 totals[NWAVES][64];

    const int map  = (int)blockIdx.x;
    const int w    = (int)(threadIdx.x >> 6);   // wave id = segment id
    const int lane = (int)(threadIdx.x & 63);

    // Reversed column mapping: lane l covers columns {126-2l, 127-2l}.
    const size_t base = (size_t)map * (W * W) + (size_t)(w * SEG) * W
                        + (size_t)(126 - 2 * lane);
    const float* __restrict__ xp = x + base;
    float* __restrict__ op = out + base;

    // Phase 1a: issue every row load in the segment (descending row order,
    // matching consumption order -> incremental vmcnt waits).
    f32x2 v[SEG];
    #pragma unroll
    for (int i = SEG - 1; i >= 0; --i)
        v[i] = *reinterpret_cast<const f32x2*>(xp + (size_t)i * W);

    // Phase 1b: bottom-up segment-local scan, in place.
    float cx = -INFINITY, cy = -INFINITY;
    #pragma unroll
    for (int i = SEG - 1; i >= 0; --i) {
        const float a  = v[i].x;          // col 126-2l
        const float b  = v[i].y;          // col 127-2l
        const float lm = fmaxf(a, b);

        // Exclusive-prefix input: lanemax from lane-1 (lane 0 -> -inf).
        int sh = __builtin_amdgcn_update_dpp(
            __float_as_int(lm), __float_as_int(lm), 0x138 /*wave_shr:1*/,
            0xF, 0xF, false);
        float e = (lane == 0) ? -INFINITY : __int_as_float(sh);

        // Inclusive prefix-max scan over 64 lanes (GFX9 DPP sequence).
        e = dpp_max<0x111, 0xF>(e);   // row_shr:1
        e = dpp_max<0x112, 0xF>(e);   // row_shr:2
        e = dpp_max<0x114, 0xF>(e);   // row_shr:4
        e = dpp_max<0x118, 0xF>(e);   // row_shr:8
        e = dpp_max<0x142, 0xA>(e);   // row_bcast15 -> lanes 16-31, 48-63
        e = dpp_max<0x143, 0xC>(e);   // row_bcast31 -> lanes 32-63

        // Row-suffix values at this lane's two columns:
        //   col 127-2l: max(b, e);  col 126-2l: max(a, b, e) = max(lm, e).
        cx = fmaxf(cx, fmaxf(lm, e));
        cy = fmaxf(cy, fmaxf(b, e));
        v[i].x = cx;
        v[i].y = cy;
    }

    // Phase 2: exchange per-column segment totals; fold segments below.
    totals[w][lane] = (f32x2){cx, cy};
    __syncthreads();

    float fx = -INFINITY, fy = -INFINITY;
    for (int w2 = w + 1; w2 < NWAVES; ++w2) {   // wave-uniform trip count
        const f32x2 t = totals[w2][lane];
        fx = fmaxf(fx, t.x);
        fy = fmaxf(fy, t.y);
    }

    // Phase 3: fold and stream out, non-temporal (don't allocate in L3 --
    // keep the input resident there instead).
    #pragma unroll
    for (int i = 0; i < SEG; ++i) {
        f32x2 o;
        o.x = fmaxf(v[i].x, fx);
        o.y = fmaxf(v[i].y, fy);
        __builtin_nontemporal_store(
            o, reinterpret_cast<f32x2*>(op + (size_t)i * W));
    }
}

extern "C" void kernel_launch(void* const* d_in, const int* in_sizes, int n_in,
                              void* d_out, int out_size, void* d_ws, size_t ws_size,
                              hipStream_t stream) {
    (void)in_sizes; (void)n_in; (void)out_size; (void)d_ws; (void)ws_size;
    const float* x = (const float*)d_in[0];
    float* out = (float*)d_out;

    // One block (8 waves) per map.
    dim3 grid(N_MAPS);
    dim3 block(64 * NWAVES);
    hipLaunchKernelGGL(TopLeftPool_54357106098212_kernel, grid, block, 0, stream,
                       x, out);
}